// Round 1
// baseline (2902.494 us; speedup 1.0000x reference)
//
#include <hip/hip_runtime.h>
#include <stdint.h>

#define HD 64

typedef _Float16 f16x2 __attribute__((ext_vector_type(2)));

union H2U { uint32_t u; f16x2 h; };

__device__ __forceinline__ float fdot2f(f16x2 a, f16x2 b, float c) {
#if __has_builtin(__builtin_amdgcn_fdot2)
  return __builtin_amdgcn_fdot2(a, b, c, false);
#else
  return fmaf((float)a[1], (float)b[1], fmaf((float)a[0], (float)b[0], c));
#endif
}

__device__ __forceinline__ float fast_exp2(float x) {
#if __has_builtin(__builtin_amdgcn_exp2f)
  return __builtin_amdgcn_exp2f(x);
#else
  return exp2f(x);
#endif
}

__device__ __forceinline__ float fast_rcp(float x) {
#if __has_builtin(__builtin_amdgcn_rcpf)
  return __builtin_amdgcn_rcpf(x);
#else
  return 1.0f / x;
#endif
}

// Degree-4 Taylor jet of tanh: input jet u0..u4, output jet t0..t4.
// t' = (1 - t^2) u'  => standard series recurrence.
__device__ __forceinline__ void tanh_jets(float u0, float u1, float u2, float u3, float u4,
                                          float& t0, float& t1, float& t2, float& t3, float& t4) {
  // e = exp(2*u0) computed via exp2; clamp to avoid inf -> NaN in v0.
  float aa = fminf(2.8853900817779268f * u0, 126.0f);   // 2*log2(e)*u0
  float e  = fast_exp2(aa);
  float r  = fast_rcp(e + 1.0f);
  t0 = fmaf(-2.0f, r, 1.0f);                 // tanh(u0)
  float v0 = 4.0f * e * (r * r);             // sech^2(u0), no cancellation
  t1 = v0 * u1;
  float v1 = -2.0f * t0 * t1;
  t2 = fmaf(u2, v0, 0.5f * u1 * v1);
  float v2 = -fmaf(2.0f * t0, t2, t1 * t1);
  t3 = fmaf(u3, v0, fmaf(0.6666666667f * u2, v1, 0.3333333333f * u1 * v2));
  float v3 = -2.0f * fmaf(t0, t3, t1 * t2);
  t4 = fmaf(u4, v0, fmaf(0.75f * u3, v1, fmaf(0.5f * u2, v2, 0.25f * u1 * v3)));
}

// Pack weights into dot2-friendly layouts in d_ws (all uniform, read via s_load later).
// ws layout (dwords):
//   [0    .. 511 ]  P1: [h][8] floats = {W1[0][h],W1[1][h],W1[2][h],W1[3][h],b1[h],0,0,0}
//   [512  .. 2559]  W2pack: [h][32] half2 = (W2[2cp][h], W2[2cp+1][h])
//   [2560 .. 4607]  W3pack: same for W3
//   [4608 .. 4639]  W4pack: [32] half2 = (W4[2cp], W4[2cp+1])
__global__ void prep_kernel(const float* __restrict__ W1, const float* __restrict__ b1,
                            const float* __restrict__ W2, const float* __restrict__ W3,
                            const float* __restrict__ W4, uint32_t* __restrict__ ws) {
  const int t = threadIdx.x;  // 256 threads, 1 block
  float* P1 = (float*)ws;
  if (t < 64) {
    P1[t * 8 + 0] = W1[0 * 64 + t];
    P1[t * 8 + 1] = W1[1 * 64 + t];
    P1[t * 8 + 2] = W1[2 * 64 + t];
    P1[t * 8 + 3] = W1[3 * 64 + t];
    P1[t * 8 + 4] = b1[t];
    P1[t * 8 + 5] = 0.f; P1[t * 8 + 6] = 0.f; P1[t * 8 + 7] = 0.f;
  }
  for (int idx = t; idx < 2048; idx += 256) {
    int h = idx >> 5, cp = idx & 31;
    H2U a; a.h[0] = (_Float16)W2[(2 * cp) * 64 + h]; a.h[1] = (_Float16)W2[(2 * cp + 1) * 64 + h];
    ws[512 + idx] = a.u;
    H2U b; b.h[0] = (_Float16)W3[(2 * cp) * 64 + h]; b.h[1] = (_Float16)W3[(2 * cp + 1) * 64 + h];
    ws[2560 + idx] = b.u;
  }
  if (t < 32) {
    H2U a; a.h[0] = (_Float16)W4[2 * t]; a.h[1] = (_Float16)W4[2 * t + 1];
    ws[4608 + t] = a.u;
  }
}

__global__ __launch_bounds__(64, 1)
void beam_kernel(const float* __restrict__ X, const float* __restrict__ Ein,
                 const float* __restrict__ Iin, const float* __restrict__ Qin,
                 const float* __restrict__ b2, const float* __restrict__ b3,
                 const float* __restrict__ b4, const uint32_t* __restrict__ ws,
                 float* __restrict__ out, int n) {
  // Per-lane LDS scratch: 64 lanes * 640 B = 40960 B. Layout inside a slice:
  // f16 at byte pos = k*128 + 2*h (k = jet index 0..4, h = hidden unit 0..63),
  // every byte position XOR'd with ((lane&15)<<3) to spread banks.
  __shared__ uint64_t lds8[5120];
  uint8_t* lds = (uint8_t*)lds8;
  const int lane = threadIdx.x;
  const int i = blockIdx.x * 64 + lane;
  if (i >= n) return;
  const uint32_t sbase = (uint32_t)lane * 640u;
  const uint32_t xr = ((uint32_t)lane & 15u) << 3;

  const float x  = X[i];
  const float Ev = Ein[i], Iv = Iin[i], qv = Qin[i];
  const float f1 = Ev * 5.0e-12f;   // E / 2e11
  const float f2 = Iv * 1.0e6f;     // I / 1e-6
  const float f3 = qv * 1.0e-3f;    // q / 1e3
  const float s  = qv * fast_rcp(fmaf(Ev, Iv, 1.1920929e-7f));  // q*L^4/(E*I+eps), L=1

  // Activation jets, packed f16 pairs over the hidden dim: T_k[cp] = (t_k[2cp], t_k[2cp+1])
  f16x2 T0[32], T1[32], T2[32], T3[32], T4[32];

  const float*    P1  = (const float*)ws;
  const uint32_t* W2p = ws + 512;
  const uint32_t* W3p = ws + 2560;
  const uint32_t* W4p = ws + 4608;

  float e0, e1, e2, e3, e4;  // even-h staging for paired LDS writes

  auto write_pair = [&](int hev, float t0, float t1, float t2, float t3, float t4) {
    H2U w0, w1, w2, w3, w4;
    w0.h[0] = (_Float16)e0; w0.h[1] = (_Float16)t0;
    w1.h[0] = (_Float16)e1; w1.h[1] = (_Float16)t1;
    w2.h[0] = (_Float16)e2; w2.h[1] = (_Float16)t2;
    w3.h[0] = (_Float16)e3; w3.h[1] = (_Float16)t3;
    w4.h[0] = (_Float16)e4; w4.h[1] = (_Float16)t4;
    uint32_t pb = (uint32_t)(2 * hev);
    *(uint32_t*)(lds + sbase + ((pb + 0u)   ^ xr)) = w0.u;
    *(uint32_t*)(lds + sbase + ((pb + 128u) ^ xr)) = w1.u;
    *(uint32_t*)(lds + sbase + ((pb + 256u) ^ xr)) = w2.u;
    *(uint32_t*)(lds + sbase + ((pb + 384u) ^ xr)) = w3.u;
    *(uint32_t*)(lds + sbase + ((pb + 512u) ^ xr)) = w4.u;
  };

  auto readback = [&]() {
    #pragma unroll
    for (int r = 0; r < 80; ++r) {
      union { uint64_t u; uint32_t w[2]; } v;
      v.u = *(const uint64_t*)(lds + sbase + (((uint32_t)(r * 8)) ^ xr));
      H2U lo, hi; lo.u = v.w[0]; hi.u = v.w[1];
      const int k = r >> 4, qq = r & 15;
      if      (k == 0) { T0[2*qq] = lo.h; T0[2*qq+1] = hi.h; }
      else if (k == 1) { T1[2*qq] = lo.h; T1[2*qq+1] = hi.h; }
      else if (k == 2) { T2[2*qq] = lo.h; T2[2*qq+1] = hi.h; }
      else if (k == 3) { T3[2*qq] = lo.h; T3[2*qq+1] = hi.h; }
      else             { T4[2*qq] = lo.h; T4[2*qq+1] = hi.h; }
    }
  };

  // ---- Layer 1: input jet is ([x,f1,f2,f3], d/dx = [1,0,0,0]) ----
  for (int h = 0; h < HD; ++h) {
    const float a0 = P1[h*8+0], a1 = P1[h*8+1], a2 = P1[h*8+2], a3 = P1[h*8+3], a4 = P1[h*8+4];
    float u0 = fmaf(a0, x, fmaf(a1, f1, fmaf(a2, f2, fmaf(a3, f3, a4))));
    float t0, t1, t2, t3, t4;
    tanh_jets(u0, a0, 0.f, 0.f, 0.f, t0, t1, t2, t3, t4);
    if (h & 1) write_pair(h - 1, t0, t1, t2, t3, t4);
    else { e0 = t0; e1 = t1; e2 = t2; e3 = t3; e4 = t4; }
  }
  readback();

  // ---- Layers 2 and 3: z_k[h] = sum_c W[c][h] * t_k[c]  (+bias on k=0), then tanh jets ----
  auto dense_layer = [&](const uint32_t* __restrict__ Wp, const float* __restrict__ bias) {
    for (int h = 0; h < HD; ++h) {
      float z0 = bias[h], z1 = 0.f, z2 = 0.f, z3 = 0.f, z4 = 0.f;
      #pragma unroll
      for (int cp = 0; cp < 32; ++cp) {
        H2U w; w.u = Wp[h * 32 + cp];   // uniform -> s_load; one SGPR operand per dot2
        z0 = fdot2f(T0[cp], w.h, z0);
        z1 = fdot2f(T1[cp], w.h, z1);
        z2 = fdot2f(T2[cp], w.h, z2);
        z3 = fdot2f(T3[cp], w.h, z3);
        z4 = fdot2f(T4[cp], w.h, z4);
      }
      float t0, t1, t2, t3, t4;
      tanh_jets(z0, z1, z2, z3, z4, t0, t1, t2, t3, t4);
      if (h & 1) write_pair(h - 1, t0, t1, t2, t3, t4);
      else { e0 = t0; e1 = t1; e2 = t2; e3 = t3; e4 = t4; }
    }
    readback();
  };
  dense_layer(W2p, b2);
  dense_layer(W3p, b3);

  // ---- Layer 4 (64 -> 1) ----
  float p0 = b4[0], p1 = 0.f, p2 = 0.f, p3 = 0.f, p4 = 0.f;
  #pragma unroll
  for (int cp = 0; cp < 32; ++cp) {
    H2U w; w.u = W4p[cp];
    p0 = fdot2f(T0[cp], w.h, p0);
    p1 = fdot2f(T1[cp], w.h, p1);
    p2 = fdot2f(T2[cp], w.h, p2);
    p3 = fdot2f(T3[cp], w.h, p3);
    p4 = fdot2f(T4[cp], w.h, p4);
  }

  // Taylor coeffs -> derivatives: psi^(k) = k! * p_k
  const float psi   = p0;
  const float px    = p1;
  const float pxx   = 2.0f * p2;
  const float pxxx  = 6.0f * p3;
  const float pxxxx = 24.0f * p4;
  const float x2 = x * x;

  out[0 * n + i] = s * (x2 * psi);
  out[1 * n + i] = s * fmaf(2.0f * x, psi, x2 * px);
  out[2 * n + i] = s * (fmaf(4.0f * x, px, 2.0f * psi) + x2 * pxx);
  out[3 * n + i] = s * (fmaf(6.0f * x, pxx, 6.0f * px) + x2 * pxxx);
  out[4 * n + i] = s * (fmaf(8.0f * x, pxxx, 12.0f * pxx) + x2 * pxxxx);
}

extern "C" void kernel_launch(void* const* d_in, const int* in_sizes, int n_in,
                              void* d_out, int out_size, void* d_ws, size_t ws_size,
                              hipStream_t stream) {
  const float* X  = (const float*)d_in[0];
  const float* E  = (const float*)d_in[1];
  const float* I  = (const float*)d_in[2];
  const float* q  = (const float*)d_in[3];
  const float* W1 = (const float*)d_in[4];
  const float* b1 = (const float*)d_in[5];
  const float* W2 = (const float*)d_in[6];
  const float* b2 = (const float*)d_in[7];
  const float* W3 = (const float*)d_in[8];
  const float* b3 = (const float*)d_in[9];
  const float* W4 = (const float*)d_in[10];
  const float* b4 = (const float*)d_in[11];
  const int n = in_sizes[0];
  uint32_t* ws = (uint32_t*)d_ws;   // needs ~18.6 KB
  float* out = (float*)d_out;

  prep_kernel<<<dim3(1), dim3(256), 0, stream>>>(W1, b1, W2, W3, W4, ws);
  beam_kernel<<<dim3((n + 63) / 64), dim3(64), 0, stream>>>(X, E, I, q, b2, b3, b4, ws, out, n);
}

// Round 3
// 311.911 us; speedup vs baseline: 9.3055x; 9.3055x over previous
//
#include <hip/hip_runtime.h>
#include <stdint.h>

#define HD 64

typedef _Float16 f16x2 __attribute__((ext_vector_type(2)));
typedef uint32_t u32a __attribute__((may_alias));
typedef uint64_t u64a __attribute__((may_alias));

union H2U { uint32_t u; f16x2 h; };

__device__ __forceinline__ float fdot2f(f16x2 a, f16x2 b, float c) {
#if __has_builtin(__builtin_amdgcn_fdot2)
  return __builtin_amdgcn_fdot2(a, b, c, false);
#else
  return fmaf((float)a[1], (float)b[1], fmaf((float)a[0], (float)b[0], c));
#endif
}

__device__ __forceinline__ float fast_exp2(float x) {
#if __has_builtin(__builtin_amdgcn_exp2f)
  return __builtin_amdgcn_exp2f(x);
#else
  return exp2f(x);
#endif
}

__device__ __forceinline__ float fast_rcp(float x) {
#if __has_builtin(__builtin_amdgcn_rcpf)
  return __builtin_amdgcn_rcpf(x);
#else
  return 1.0f / x;
#endif
}

// Degree-4 Taylor jet of tanh: input jet u0..u4 -> output jet t0..t4.
__device__ __forceinline__ void tanh_jets(float u0, float u1, float u2, float u3, float u4,
                                          float& t0, float& t1, float& t2, float& t3, float& t4) {
  float aa = fminf(2.8853900817779268f * u0, 126.0f);   // 2*log2(e)*u0
  float e  = fast_exp2(aa);
  float r  = fast_rcp(e + 1.0f);
  t0 = fmaf(-2.0f, r, 1.0f);                 // tanh(u0)
  float v0 = 4.0f * e * (r * r);             // sech^2(u0)
  t1 = v0 * u1;
  float v1 = -2.0f * t0 * t1;
  t2 = fmaf(u2, v0, 0.5f * u1 * v1);
  float v2 = -fmaf(2.0f * t0, t2, t1 * t1);
  t3 = fmaf(u3, v0, fmaf(0.6666666667f * u2, v1, 0.3333333333f * u1 * v2));
  float v3 = -2.0f * fmaf(t0, t3, t1 * t2);
  t4 = fmaf(u4, v0, fmaf(0.75f * u3, v1, fmaf(0.5f * u2, v2, 0.25f * u1 * v3)));
}

// ws layout (dwords):
//   [0    .. 511 ]  P1: [h][8] floats = {W1[0][h],W1[1][h],W1[2][h],W1[3][h],b1[h],0,0,0}
//   [512  .. 2559]  W2pack: [h][32] half2 = (W2[2c][h], W2[2c+1][h])
//   [2560 .. 4607]  W3pack: same for W3
//   [4608 .. 4639]  W4pack: [32] half2 = (W4[2c], W4[2c+1])
__global__ void prep_kernel(const float* __restrict__ W1, const float* __restrict__ b1,
                            const float* __restrict__ W2, const float* __restrict__ W3,
                            const float* __restrict__ W4, uint32_t* __restrict__ ws) {
  const int t = threadIdx.x;  // 256 threads, 1 block
  float* P1 = (float*)ws;
  if (t < 64) {
    P1[t * 8 + 0] = W1[0 * 64 + t];
    P1[t * 8 + 1] = W1[1 * 64 + t];
    P1[t * 8 + 2] = W1[2 * 64 + t];
    P1[t * 8 + 3] = W1[3 * 64 + t];
    P1[t * 8 + 4] = b1[t];
    P1[t * 8 + 5] = 0.f; P1[t * 8 + 6] = 0.f; P1[t * 8 + 7] = 0.f;
  }
  for (int idx = t; idx < 2048; idx += 256) {
    int h = idx >> 5, cp = idx & 31;
    H2U a; a.h[0] = (_Float16)W2[(2 * cp) * 64 + h]; a.h[1] = (_Float16)W2[(2 * cp + 1) * 64 + h];
    ws[512 + idx] = a.u;
    H2U b; b.h[0] = (_Float16)W3[(2 * cp) * 64 + h]; b.h[1] = (_Float16)W3[(2 * cp + 1) * 64 + h];
    ws[2560 + idx] = b.u;
  }
  if (t < 32) {
    H2U a; a.h[0] = (_Float16)W4[2 * t]; a.h[1] = (_Float16)W4[2 * t + 1];
    ws[4608 + t] = a.u;
  }
}

// ---- preprocessor unrolling machinery: NO arrays, NO lambdas ----
#define RPT32(M) M(0) M(1) M(2) M(3) M(4) M(5) M(6) M(7) M(8) M(9) M(10) M(11) M(12) M(13) M(14) M(15) \
                 M(16) M(17) M(18) M(19) M(20) M(21) M(22) M(23) M(24) M(25) M(26) M(27) M(28) M(29) M(30) M(31)
#define RPT16P(M) M(0,1) M(2,3) M(4,5) M(6,7) M(8,9) M(10,11) M(12,13) M(14,15) \
                  M(16,17) M(18,19) M(20,21) M(22,23) M(24,25) M(26,27) M(28,29) M(30,31)

// 160 individually named f16x2 activation-jet pair registers
#define DECLT(c) f16x2 T0_##c, T1_##c, T2_##c, T3_##c, T4_##c;

// readback one b64 (two pairs) for jet k at pair indices c0,c0+1 (may_alias type!)
#define RBK(k, c0, c1) { \
    uint64_t v_ = *(const u64a*)(lds + sbase + (((uint32_t)((k)*128 + (c0)*4)) ^ xr)); \
    H2U lo_, hi_; lo_.u = (uint32_t)v_; hi_.u = (uint32_t)(v_ >> 32); \
    T##k##_##c0 = lo_.h; T##k##_##c1 = hi_.h; }
#define RB0(c0,c1) RBK(0,c0,c1)
#define RB1(c0,c1) RBK(1,c0,c1)
#define RB2(c0,c1) RBK(2,c0,c1)
#define RB3(c0,c1) RBK(3,c0,c1)
#define RB4(c0,c1) RBK(4,c0,c1)
// compiler fence first: ds_writes must not be reordered past the readback loads
#define READBACK  asm volatile("" ::: "memory"); \
                  RPT16P(RB0) RPT16P(RB1) RPT16P(RB2) RPT16P(RB3) RPT16P(RB4) \
                  asm volatile("" ::: "memory");

// accumulate one weight pair into the 5 jet accumulators
#define ACC(c) { H2U w_; w_.u = row[c]; \
    z0 = fdot2f(T0_##c, w_.h, z0); \
    z1 = fdot2f(T1_##c, w_.h, z1); \
    z2 = fdot2f(T2_##c, w_.h, z2); \
    z3 = fdot2f(T3_##c, w_.h, z3); \
    z4 = fdot2f(T4_##c, w_.h, z4); }

// stage/write the 5-jet f16 outputs for unit h (pairs of h written together; may_alias stores)
#define WRITE_OR_STAGE(h, t0, t1, t2, t3, t4) \
  if ((h) & 1) { \
    H2U w0_, w1_, w2_, w3_, w4_; \
    w0_.h[0] = (_Float16)e0; w0_.h[1] = (_Float16)(t0); \
    w1_.h[0] = (_Float16)e1; w1_.h[1] = (_Float16)(t1); \
    w2_.h[0] = (_Float16)e2; w2_.h[1] = (_Float16)(t2); \
    w3_.h[0] = (_Float16)e3; w3_.h[1] = (_Float16)(t3); \
    w4_.h[0] = (_Float16)e4; w4_.h[1] = (_Float16)(t4); \
    uint32_t pb_ = (uint32_t)(2 * ((h) - 1)); \
    *(u32a*)(lds + sbase + ((pb_ +   0u) ^ xr)) = w0_.u; \
    *(u32a*)(lds + sbase + ((pb_ + 128u) ^ xr)) = w1_.u; \
    *(u32a*)(lds + sbase + ((pb_ + 256u) ^ xr)) = w2_.u; \
    *(u32a*)(lds + sbase + ((pb_ + 384u) ^ xr)) = w3_.u; \
    *(u32a*)(lds + sbase + ((pb_ + 512u) ^ xr)) = w4_.u; \
  } else { e0 = (t0); e1 = (t1); e2 = (t2); e3 = (t3); e4 = (t4); }

#define DENSE_LAYER(WPTR, BIAS) { \
    _Pragma("unroll 2") \
    for (int h = 0; h < HD; ++h) { \
      const uint32_t* row = (WPTR) + h * 32; \
      float z0 = (BIAS)[h], z1 = 0.f, z2 = 0.f, z3 = 0.f, z4 = 0.f; \
      RPT32(ACC) \
      float t0, t1, t2, t3, t4; \
      tanh_jets(z0, z1, z2, z3, z4, t0, t1, t2, t3, t4); \
      WRITE_OR_STAGE(h, t0, t1, t2, t3, t4) \
    } \
    READBACK }

// layer-4 accumulate
#define ACC4(c) { H2U w_; w_.u = W4p[c]; \
    p0 = fdot2f(T0_##c, w_.h, p0); \
    p1 = fdot2f(T1_##c, w_.h, p1); \
    p2 = fdot2f(T2_##c, w_.h, p2); \
    p3 = fdot2f(T3_##c, w_.h, p3); \
    p4 = fdot2f(T4_##c, w_.h, p4); }

__global__ __launch_bounds__(64, 1)
void beam_kernel(const float* __restrict__ X, const float* __restrict__ Ein,
                 const float* __restrict__ Iin, const float* __restrict__ Qin,
                 const float* __restrict__ b2, const float* __restrict__ b3,
                 const float* __restrict__ b4, const uint32_t* __restrict__ ws,
                 float* __restrict__ out, int n) {
  // Per-lane LDS scratch: 64 lanes * 640 B. f16 at byte pos = k*128 + 2*h,
  // XOR-swizzled by ((lane&15)<<3) (bijective within the 640B slice).
  __shared__ uint64_t lds8[5120];
  uint8_t* lds = (uint8_t*)lds8;
  const int lane = threadIdx.x;
  int i = blockIdx.x * 64 + lane;
  i = (i < n) ? i : (n - 1);   // clamp (no divergent return -> keeps weight loads scalar)
  const uint32_t sbase = (uint32_t)lane * 640u;
  const uint32_t xr = ((uint32_t)lane & 15u) << 3;

  const float x  = X[i];
  const float Ev = Ein[i], Iv = Iin[i], qv = Qin[i];
  const float f1 = Ev * 5.0e-12f;   // E / 2e11
  const float f2 = Iv * 1.0e6f;     // I / 1e-6
  const float f3 = qv * 1.0e-3f;    // q / 1e3
  const float s  = qv * fast_rcp(fmaf(Ev, Iv, 1.1920929e-7f));  // q/(E*I+eps)

  const float*    P1  = (const float*)ws;
  const uint32_t* W2p = ws + 512;
  const uint32_t* W3p = ws + 2560;
  const uint32_t* W4p = ws + 4608;

  RPT32(DECLT)                       // 160 named f16x2 registers
  float e0, e1, e2, e3, e4;          // even-h staging

  // ---- Layer 1: input jet ([x,f1,f2,f3], d/dx = [1,0,0,0]) ----
  #pragma unroll 2
  for (int h = 0; h < HD; ++h) {
    const float a0 = P1[h*8+0], a1 = P1[h*8+1], a2 = P1[h*8+2], a3 = P1[h*8+3], a4 = P1[h*8+4];
    float u0 = fmaf(a0, x, fmaf(a1, f1, fmaf(a2, f2, fmaf(a3, f3, a4))));
    float t0, t1, t2, t3, t4;
    tanh_jets(u0, a0, 0.f, 0.f, 0.f, t0, t1, t2, t3, t4);
    WRITE_OR_STAGE(h, t0, t1, t2, t3, t4)
  }
  READBACK

  // ---- Layers 2 and 3 ----
  DENSE_LAYER(W2p, b2)
  DENSE_LAYER(W3p, b3)

  // ---- Layer 4 (64 -> 1) ----
  float p0 = b4[0], p1 = 0.f, p2 = 0.f, p3 = 0.f, p4 = 0.f;
  RPT32(ACC4)

  // Taylor coeffs -> derivatives: psi^(k) = k! * p_k
  const float psi   = p0;
  const float px    = p1;
  const float pxx   = 2.0f * p2;
  const float pxxx  = 6.0f * p3;
  const float pxxxx = 24.0f * p4;
  const float x2 = x * x;

  out[0 * n + i] = s * (x2 * psi);
  out[1 * n + i] = s * fmaf(2.0f * x, psi, x2 * px);
  out[2 * n + i] = s * (fmaf(4.0f * x, px, 2.0f * psi) + x2 * pxx);
  out[3 * n + i] = s * (fmaf(6.0f * x, pxx, 6.0f * px) + x2 * pxxx);
  out[4 * n + i] = s * (fmaf(8.0f * x, pxxx, 12.0f * pxx) + x2 * pxxxx);
}

extern "C" void kernel_launch(void* const* d_in, const int* in_sizes, int n_in,
                              void* d_out, int out_size, void* d_ws, size_t ws_size,
                              hipStream_t stream) {
  const float* X  = (const float*)d_in[0];
  const float* E  = (const float*)d_in[1];
  const float* I  = (const float*)d_in[2];
  const float* q  = (const float*)d_in[3];
  const float* W1 = (const float*)d_in[4];
  const float* b1 = (const float*)d_in[5];
  const float* W2 = (const float*)d_in[6];
  const float* b2 = (const float*)d_in[7];
  const float* W3 = (const float*)d_in[8];
  const float* b3 = (const float*)d_in[9];
  const float* W4 = (const float*)d_in[10];
  const float* b4 = (const float*)d_in[11];
  const int n = in_sizes[0];
  uint32_t* ws = (uint32_t*)d_ws;
  float* out = (float*)d_out;

  prep_kernel<<<dim3(1), dim3(256), 0, stream>>>(W1, b1, W2, W3, W4, ws);
  beam_kernel<<<dim3((n + 63) / 64), dim3(64), 0, stream>>>(X, E, I, q, b2, b3, b4, ws, out, n);
}

// Round 4
// 76.909 us; speedup vs baseline: 37.7393x; 4.0556x over previous
//
#include <hip/hip_runtime.h>
#include <stdint.h>

typedef _Float16 f16x8 __attribute__((ext_vector_type(8)));
typedef float    f32x4 __attribute__((ext_vector_type(4)));
typedef _Float16 f16a  __attribute__((may_alias));
typedef uint32_t u32a  __attribute__((may_alias));
typedef uint4    u128a __attribute__((may_alias));

union HU   { uint32_t u; _Float16 h[2]; };
union B128 { uint4 q; f16x8 v; };

__device__ __forceinline__ float fast_exp2(float x) {
#if __has_builtin(__builtin_amdgcn_exp2f)
  return __builtin_amdgcn_exp2f(x);
#else
  return exp2f(x);
#endif
}
__device__ __forceinline__ float fast_rcp(float x) {
#if __has_builtin(__builtin_amdgcn_rcpf)
  return __builtin_amdgcn_rcpf(x);
#else
  return 1.0f / x;
#endif
}

// Degree-4 Taylor jet of tanh: input jet u0..u4 -> output jet t0..t4.
__device__ __forceinline__ void tanh_jets(float u0, float u1, float u2, float u3, float u4,
                                          float& t0, float& t1, float& t2, float& t3, float& t4) {
  float aa = fminf(2.8853900817779268f * u0, 126.0f);   // 2*log2(e)*u0
  float e  = fast_exp2(aa);
  float r  = fast_rcp(e + 1.0f);
  t0 = fmaf(-2.0f, r, 1.0f);                 // tanh(u0)
  float v0 = 4.0f * e * (r * r);             // sech^2(u0)
  t1 = v0 * u1;
  float v1 = -2.0f * t0 * t1;
  t2 = fmaf(u2, v0, 0.5f * u1 * v1);
  float v2 = -fmaf(2.0f * t0, t2, t1 * t1);
  t3 = fmaf(u3, v0, fmaf(0.6666666667f * u2, v1, 0.3333333333f * u1 * v2));
  float v3 = -2.0f * fmaf(t0, t3, t1 * t2);
  t4 = fmaf(u4, v0, fmaf(0.75f * u3, v1, fmaf(0.5f * u2, v2, 0.25f * u1 * v3)));
}

// ws layout (dwords):
//   [0    .. 511 ]  P1: [h][8] floats = {W1[0][h],W1[1][h],W1[2][h],W1[3][h],b1[h],0,0,0}
//   [512  .. 2559]  W2 B-frags: frag fi=tn*2+s, lane l, 4 dwords (8 halves):
//                   half j of (fi,l) = W2[k][nn], k=32s+8*(l>>4)+j, nn=16*tn+(l&15)
//   [2560 .. 4607]  W3 B-frags: same map
//   [4608 .. 4639]  W4pack: [32] half2 = (W4[2c], W4[2c+1])
__global__ void prep_kernel(const float* __restrict__ W1, const float* __restrict__ b1,
                            const float* __restrict__ W2, const float* __restrict__ W3,
                            const float* __restrict__ W4, uint32_t* __restrict__ ws) {
  const int t = threadIdx.x;  // 256 threads, 1 block
  float* P1 = (float*)ws;
  if (t < 64) {
    P1[t * 8 + 0] = W1[0 * 64 + t];
    P1[t * 8 + 1] = W1[1 * 64 + t];
    P1[t * 8 + 2] = W1[2 * 64 + t];
    P1[t * 8 + 3] = W1[3 * 64 + t];
    P1[t * 8 + 4] = b1[t];
    P1[t * 8 + 5] = 0.f; P1[t * 8 + 6] = 0.f; P1[t * 8 + 7] = 0.f;
  }
  for (int idx = t; idx < 2048; idx += 256) {
    int fi = idx >> 8;            // frag index 0..7 = tn*2 + s
    int tn = fi >> 1, s = fi & 1;
    int l  = (idx >> 2) & 63;     // lane
    int pj = idx & 3;             // pair-of-j (j0 = 2*pj)
    int k  = 32 * s + 8 * (l >> 4) + 2 * pj;
    int nn = 16 * tn + (l & 15);
    HU a; a.h[0] = (_Float16)W2[k * 64 + nn]; a.h[1] = (_Float16)W2[(k + 1) * 64 + nn];
    ws[512 + idx] = a.u;
    HU b; b.h[0] = (_Float16)W3[k * 64 + nn]; b.h[1] = (_Float16)W3[(k + 1) * 64 + nn];
    ws[2560 + idx] = b.u;
  }
  if (t < 32) {
    HU a; a.h[0] = (_Float16)W4[2 * t]; a.h[1] = (_Float16)W4[2 * t + 1];
    ws[4608 + t] = a.u;
  }
}

#define MFMA16(A, B, C) __builtin_amdgcn_mfma_f32_16x16x32_f16((A), (B), (C), 0, 0, 0)

// One dense 64->64 layer with 5 jets. LDS slice sl holds previous activations
// as [jet][point p][h] f16, byte addr = jet*2048 + p*128 + ((2h) ^ ((p&7)<<4)).
// Reads A-frags, does 40 MFMA, tanh-jets, writes new activations (same slice).
__device__ __forceinline__ void dense_layer(uint8_t* sl, int l,
                                            const uint32_t* __restrict__ frags,
                                            const float* __restrict__ bias) {
  const int g = l >> 4;
  const int p = l & 15;
  const uint32_t xorp = ((uint32_t)(p & 7)) << 4;

  // bias for the 4 h-tiles this lane's C-columns touch (col = l&15 = p)
  float bv0 = bias[p], bv1 = bias[16 + p], bv2 = bias[32 + p], bv3 = bias[48 + p];

  // B fragments (prepacked; lane-dependent)
  f16x8 Bf[4][2];
  #pragma unroll
  for (int t = 0; t < 4; ++t) {
    #pragma unroll
    for (int s = 0; s < 2; ++s) {
      B128 tmp; tmp.q = *(const u128a*)(frags + ((t * 2 + s) * 64 + l) * 4);
      Bf[t][s] = tmp.v;
    }
  }

  f32x4 acc[5][4];
  #pragma unroll
  for (int k = 0; k < 5; ++k)
    #pragma unroll
    for (int t = 0; t < 4; ++t)
      acc[k][t] = (f32x4){0.f, 0.f, 0.f, 0.f};

  asm volatile("" ::: "memory");
  #pragma unroll
  for (int s = 0; s < 2; ++s) {
    // A-frag: lane supplies row p, k-slots h = 32s + 8g + j (j=0..7) -> one b128
    const uint32_t ra = (uint32_t)(p * 128) + (((uint32_t)(64 * s + 16 * g)) ^ xorp);
    f16x8 af[5];
    #pragma unroll
    for (int k = 0; k < 5; ++k) {
      B128 tmp; tmp.q = *(const u128a*)(sl + ra + k * 2048);
      af[k] = tmp.v;
    }
    #pragma unroll
    for (int k = 0; k < 5; ++k)
      #pragma unroll
      for (int t = 0; t < 4; ++t)
        acc[k][t] = MFMA16(af[k], Bf[t][s], acc[k][t]);
  }
  asm volatile("" ::: "memory");

  // tanh jets on each held C element, write new activations (f16) back to slice.
  #pragma unroll
  for (int t = 0; t < 4; ++t) {
    const float bvt = (t == 0) ? bv0 : (t == 1) ? bv1 : (t == 2) ? bv2 : bv3;
    #pragma unroll
    for (int r = 0; r < 4; ++r) {
      const int pr = 4 * g + r;                     // output row (point), verified C map
      float z0 = acc[0][t][r] + bvt;
      float z1 = acc[1][t][r], z2 = acc[2][t][r], z3 = acc[3][t][r], z4 = acc[4][t][r];
      float t0, t1, t2, t3, t4;
      tanh_jets(z0, z1, z2, z3, z4, t0, t1, t2, t3, t4);
      const uint32_t xq = ((uint32_t)(pr & 7)) << 4;
      const uint32_t va = (uint32_t)(pr * 128) + (((uint32_t)(2 * p + 32 * t)) ^ xq);
      *(f16a*)(sl + va)        = (_Float16)t0;
      *(f16a*)(sl + va + 2048) = (_Float16)t1;
      *(f16a*)(sl + va + 4096) = (_Float16)t2;
      *(f16a*)(sl + va + 6144) = (_Float16)t3;
      *(f16a*)(sl + va + 8192) = (_Float16)t4;
    }
  }
  asm volatile("" ::: "memory");
}

__global__ __launch_bounds__(256, 2)
void beam_kernel(const float* __restrict__ X, const float* __restrict__ Ein,
                 const float* __restrict__ Iin, const float* __restrict__ Qin,
                 const float* __restrict__ b2, const float* __restrict__ b3,
                 const float* __restrict__ b4, const uint32_t* __restrict__ ws,
                 float* __restrict__ out, int n) {
  // 4 waves/block; each wave owns a 10240B LDS slice (5 jets x 16 points x 64 h x f16)
  __shared__ uint64_t lds8[5120];
  const int tid = threadIdx.x;
  const int w   = tid >> 6;
  const int l   = tid & 63;
  uint8_t* sl = (uint8_t*)lds8 + w * 10240;
  const int g = l >> 4;
  const int p = l & 15;
  int i = (blockIdx.x * 4 + w) * 16 + p;
  if (i >= n) i = n - 1;

  const float x  = X[i];
  const float Ev = Ein[i], Iv = Iin[i], qv = Qin[i];
  const float f1 = Ev * 5.0e-12f;   // E / 2e11
  const float f2 = Iv * 1.0e6f;     // I / 1e-6
  const float f3 = qv * 1.0e-3f;    // q / 1e3
  const float sf = qv * fast_rcp(fmaf(Ev, Iv, 1.1920929e-7f));  // q/(E*I+eps)

  const float*    P1f = (const float*)ws;
  const uint32_t xorp = ((uint32_t)(p & 7)) << 4;

  // ---- Layer 1: lane covers point p, hidden units h = 16g + (0..15) ----
  #pragma unroll
  for (int hh = 0; hh < 16; ++hh) {
    const int h = 16 * g + hh;
    const float4 wv = *(const float4*)(P1f + h * 8);
    const float bb  = P1f[h * 8 + 4];
    float u0 = fmaf(wv.x, x, fmaf(wv.y, f1, fmaf(wv.z, f2, fmaf(wv.w, f3, bb))));
    float t0, t1, t2, t3, t4;
    tanh_jets(u0, wv.x, 0.f, 0.f, 0.f, t0, t1, t2, t3, t4);
    const uint32_t va = (uint32_t)(p * 128) + (((uint32_t)(2 * h)) ^ xorp);
    *(f16a*)(sl + va)        = (_Float16)t0;
    *(f16a*)(sl + va + 2048) = (_Float16)t1;
    *(f16a*)(sl + va + 4096) = (_Float16)t2;
    *(f16a*)(sl + va + 6144) = (_Float16)t3;
    *(f16a*)(sl + va + 8192) = (_Float16)t4;
  }
  asm volatile("" ::: "memory");

  // ---- Layers 2 and 3 (MFMA) ----
  dense_layer(sl, l, ws + 512,  b2);
  dense_layer(sl, l, ws + 2560, b3);

  // ---- Layer 4 (64 -> 1): lane handles point p, h-chunk 16g..16g+15, then reduce ----
  const uint32_t* W4p = ws + 4608;
  float w4f[16];
  #pragma unroll
  for (int d = 0; d < 8; ++d) {
    HU uu; uu.u = W4p[8 * g + d];
    w4f[2 * d]     = (float)uu.h[0];
    w4f[2 * d + 1] = (float)uu.h[1];
  }
  float zz[5];
  #pragma unroll
  for (int k = 0; k < 5; ++k) {
    const uint32_t ra0 = (uint32_t)(p * 128) + (((uint32_t)(32 * g)) ^ xorp) + (uint32_t)(k * 2048);
    const uint32_t ra1 = (uint32_t)(p * 128) + (((uint32_t)(32 * g + 16)) ^ xorp) + (uint32_t)(k * 2048);
    B128 A0, A1;
    A0.q = *(const u128a*)(sl + ra0);
    A1.q = *(const u128a*)(sl + ra1);
    float z = 0.f;
    #pragma unroll
    for (int d = 0; d < 8; ++d) z = fmaf((float)A0.v[d], w4f[d], z);
    #pragma unroll
    for (int d = 0; d < 8; ++d) z = fmaf((float)A1.v[d], w4f[8 + d], z);
    zz[k] = z;
  }
  #pragma unroll
  for (int k = 0; k < 5; ++k) {
    zz[k] += __shfl_xor(zz[k], 16, 64);
    zz[k] += __shfl_xor(zz[k], 32, 64);
  }

  if (l < 16) {
    const float psi   = zz[0] + b4[0];
    const float px    = zz[1];
    const float pxx   = 2.0f  * zz[2];
    const float pxxx  = 6.0f  * zz[3];
    const float pxxxx = 24.0f * zz[4];
    const float x2 = x * x;
    out[0 * n + i] = sf * (x2 * psi);
    out[1 * n + i] = sf * fmaf(2.0f * x, psi, x2 * px);
    out[2 * n + i] = sf * (fmaf(4.0f * x, px, 2.0f * psi) + x2 * pxx);
    out[3 * n + i] = sf * (fmaf(6.0f * x, pxx, 6.0f * px) + x2 * pxxx);
    out[4 * n + i] = sf * (fmaf(8.0f * x, pxxx, 12.0f * pxx) + x2 * pxxxx);
  }
}

extern "C" void kernel_launch(void* const* d_in, const int* in_sizes, int n_in,
                              void* d_out, int out_size, void* d_ws, size_t ws_size,
                              hipStream_t stream) {
  const float* X  = (const float*)d_in[0];
  const float* E  = (const float*)d_in[1];
  const float* I  = (const float*)d_in[2];
  const float* q  = (const float*)d_in[3];
  const float* W1 = (const float*)d_in[4];
  const float* b1 = (const float*)d_in[5];
  const float* W2 = (const float*)d_in[6];
  const float* b2 = (const float*)d_in[7];
  const float* W3 = (const float*)d_in[8];
  const float* b3 = (const float*)d_in[9];
  const float* W4 = (const float*)d_in[10];
  const float* b4 = (const float*)d_in[11];
  const int n = in_sizes[0];
  uint32_t* ws = (uint32_t*)d_ws;
  float* out = (float*)d_out;

  prep_kernel<<<dim3(1), dim3(256), 0, stream>>>(W1, b1, W2, W3, W4, ws);
  // block = 256 threads = 4 waves; each wave = 16 points -> 64 points/block
  beam_kernel<<<dim3((n + 63) / 64), dim3(256), 0, stream>>>(X, E, I, q, b2, b3, b4, ws, out, n);
}

// Round 5
// 69.705 us; speedup vs baseline: 41.6395x; 1.1033x over previous
//
#include <hip/hip_runtime.h>
#include <stdint.h>

typedef _Float16 f16x8 __attribute__((ext_vector_type(8)));
typedef float    f32x4 __attribute__((ext_vector_type(4)));
typedef _Float16 f16a  __attribute__((may_alias));
typedef uint64_t u64a  __attribute__((may_alias));
typedef uint4    u128a __attribute__((may_alias));

union HU   { uint32_t u; _Float16 h[2]; };
union B128 { uint4 q; f16x8 v; };
union P64  { uint64_t u; _Float16 h[4]; };

__device__ __forceinline__ float fast_exp2(float x) {
#if __has_builtin(__builtin_amdgcn_exp2f)
  return __builtin_amdgcn_exp2f(x);
#else
  return exp2f(x);
#endif
}
__device__ __forceinline__ float fast_rcp(float x) {
#if __has_builtin(__builtin_amdgcn_rcpf)
  return __builtin_amdgcn_rcpf(x);
#else
  return 1.0f / x;
#endif
}

// Degree-4 Taylor jet of tanh: input jet u0..u4 -> output jet t0..t4.
__device__ __forceinline__ void tanh_jets(float u0, float u1, float u2, float u3, float u4,
                                          float& t0, float& t1, float& t2, float& t3, float& t4) {
  float aa = fminf(2.8853900817779268f * u0, 126.0f);   // 2*log2(e)*u0
  float e  = fast_exp2(aa);
  float r  = fast_rcp(e + 1.0f);
  t0 = fmaf(-2.0f, r, 1.0f);                 // tanh(u0)
  float v0 = 4.0f * e * (r * r);             // sech^2(u0)
  t1 = v0 * u1;
  float v1 = -2.0f * t0 * t1;
  t2 = fmaf(u2, v0, 0.5f * u1 * v1);
  float v2 = -fmaf(2.0f * t0, t2, t1 * t1);
  t3 = fmaf(u3, v0, fmaf(0.6666666667f * u2, v1, 0.3333333333f * u1 * v2));
  float v3 = -2.0f * fmaf(t0, t3, t1 * t2);
  t4 = fmaf(u4, v0, fmaf(0.75f * u3, v1, fmaf(0.5f * u2, v2, 0.25f * u1 * v3)));
}

// ws layout (dwords) — identical packing to R4; block [512..] now serves as the
// MFMA *A* fragments (row = h_out = 16*tm + (l&15), k = h_in = 32s + 8*(l>>4) + j):
//   [0    .. 511 ]  P1: [h][8] floats = {W1[0][h],W1[1][h],W1[2][h],W1[3][h],b1[h],0,0,0}
//   [512  .. 2559]  W2 frags: frag fi=tm*2+s, lane l, 4 dwords (8 halves)
//   [2560 .. 4607]  W3 frags: same map
//   [4608 .. 4639]  W4pack: [32] half2 = (W4[2c], W4[2c+1])
__global__ void prep_kernel(const float* __restrict__ W1, const float* __restrict__ b1,
                            const float* __restrict__ W2, const float* __restrict__ W3,
                            const float* __restrict__ W4, uint32_t* __restrict__ ws) {
  const int t = threadIdx.x;  // 256 threads, 1 block
  float* P1 = (float*)ws;
  if (t < 64) {
    P1[t * 8 + 0] = W1[0 * 64 + t];
    P1[t * 8 + 1] = W1[1 * 64 + t];
    P1[t * 8 + 2] = W1[2 * 64 + t];
    P1[t * 8 + 3] = W1[3 * 64 + t];
    P1[t * 8 + 4] = b1[t];
    P1[t * 8 + 5] = 0.f; P1[t * 8 + 6] = 0.f; P1[t * 8 + 7] = 0.f;
  }
  for (int idx = t; idx < 2048; idx += 256) {
    int fi = idx >> 8;            // frag index 0..7 = tm*2 + s
    int tm = fi >> 1, s = fi & 1;
    int l  = (idx >> 2) & 63;     // lane
    int pj = idx & 3;             // pair-of-j (j0 = 2*pj)
    int k  = 32 * s + 8 * (l >> 4) + 2 * pj;
    int mm = 16 * tm + (l & 15);  // h_out row
    HU a; a.h[0] = (_Float16)W2[k * 64 + mm]; a.h[1] = (_Float16)W2[(k + 1) * 64 + mm];
    ws[512 + idx] = a.u;
    HU b; b.h[0] = (_Float16)W3[k * 64 + mm]; b.h[1] = (_Float16)W3[(k + 1) * 64 + mm];
    ws[2560 + idx] = b.u;
  }
  if (t < 32) {
    HU a; a.h[0] = (_Float16)W4[2 * t]; a.h[1] = (_Float16)W4[2 * t + 1];
    ws[4608 + t] = a.u;
  }
}

#define MFMA16(A, B, C) __builtin_amdgcn_mfma_f32_16x16x32_f16((A), (B), (C), 0, 0, 0)

// One dense 64->64 layer, 5 jets, transposed orientation:
// C = W(64x64, A-op, row=h_out) x T(64x16, B-op, col=point).
// C map (verified): col = lane&15 = point, row = 16*tm + 4*(lane>>4) + reg = h_out.
// LDS slice sl: [jet][point p][h] f16, byte = jet*2048 + p*128 + ((2h) ^ ((p&7)<<4)).
__device__ __forceinline__ void dense_layer(uint8_t* sl, int l,
                                            const uint32_t* __restrict__ frags,
                                            const float* __restrict__ bias) {
  const int g = l >> 4;
  const int p = l & 15;
  const uint32_t xorp = ((uint32_t)(p & 7)) << 4;

  // Weight A-fragments (prepacked, lane-indexed)
  f16x8 Af[4][2];
  #pragma unroll
  for (int tm = 0; tm < 4; ++tm) {
    #pragma unroll
    for (int s = 0; s < 2; ++s) {
      B128 tmp; tmp.q = *(const u128a*)(frags + ((tm * 2 + s) * 64 + l) * 4);
      Af[tm][s] = tmp.v;
    }
  }

  // acc init: bias folded into C-in (k=0 plane only). Row r of tile tm = bias[16tm+4g+r].
  f32x4 acc[5][4];
  #pragma unroll
  for (int tm = 0; tm < 4; ++tm) {
    const float4 bv = *(const float4*)(bias + 16 * tm + 4 * g);
    acc[0][tm] = (f32x4){bv.x, bv.y, bv.z, bv.w};
  }
  #pragma unroll
  for (int k = 1; k < 5; ++k)
    #pragma unroll
    for (int tm = 0; tm < 4; ++tm)
      acc[k][tm] = (f32x4){0.f, 0.f, 0.f, 0.f};

  asm volatile("" ::: "memory");
  #pragma unroll
  for (int s = 0; s < 2; ++s) {
    // B-frag: lane = col p (point), k-slots h_in = 32s + 8g + j -> one b128 per jet
    const uint32_t ra = (uint32_t)(p * 128) + (((uint32_t)(64 * s + 16 * g)) ^ xorp);
    f16x8 bf[5];
    #pragma unroll
    for (int k = 0; k < 5; ++k) {
      B128 tmp; tmp.q = *(const u128a*)(sl + ra + k * 2048);
      bf[k] = tmp.v;
    }
    #pragma unroll
    for (int k = 0; k < 5; ++k)
      #pragma unroll
      for (int tm = 0; tm < 4; ++tm)
        acc[k][tm] = MFMA16(Af[tm][s], bf[k], acc[k][tm]);
  }
  asm volatile("" ::: "memory");

  // tanh jets; lane owns point p, h_out = 16tm + 4g + r (r contiguous!) ->
  // one packed b64 write per (tile, jet).
  #pragma unroll
  for (int tm = 0; tm < 4; ++tm) {
    float tt[5][4];
    #pragma unroll
    for (int r = 0; r < 4; ++r) {
      float t0, t1, t2, t3, t4;
      tanh_jets(acc[0][tm][r], acc[1][tm][r], acc[2][tm][r], acc[3][tm][r], acc[4][tm][r],
                t0, t1, t2, t3, t4);
      tt[0][r] = t0; tt[1][r] = t1; tt[2][r] = t2; tt[3][r] = t3; tt[4][r] = t4;
    }
    const uint32_t va = (uint32_t)(p * 128) + (((uint32_t)(32 * tm + 8 * g)) ^ xorp);
    #pragma unroll
    for (int k = 0; k < 5; ++k) {
      P64 pk;
      pk.h[0] = (_Float16)tt[k][0]; pk.h[1] = (_Float16)tt[k][1];
      pk.h[2] = (_Float16)tt[k][2]; pk.h[3] = (_Float16)tt[k][3];
      *(u64a*)(sl + va + k * 2048) = pk.u;
    }
  }
  asm volatile("" ::: "memory");
}

__global__ __launch_bounds__(256, 4)
void beam_kernel(const float* __restrict__ X, const float* __restrict__ Ein,
                 const float* __restrict__ Iin, const float* __restrict__ Qin,
                 const float* __restrict__ b2, const float* __restrict__ b3,
                 const float* __restrict__ b4, const uint32_t* __restrict__ ws,
                 float* __restrict__ out, int n) {
  // 4 waves/block; each wave owns a 10240B LDS slice (5 jets x 16 points x 64 h x f16)
  __shared__ uint64_t lds8[5120];
  const int tid = threadIdx.x;
  const int w   = tid >> 6;
  const int l   = tid & 63;
  uint8_t* sl = (uint8_t*)lds8 + w * 10240;
  const int g = l >> 4;
  const int p = l & 15;
  int i = (blockIdx.x * 4 + w) * 16 + p;
  if (i >= n) i = n - 1;

  const float x  = X[i];
  const float Ev = Ein[i], Iv = Iin[i], qv = Qin[i];
  const float f1 = Ev * 5.0e-12f;   // E / 2e11
  const float f2 = Iv * 1.0e6f;     // I / 1e-6
  const float f3 = qv * 1.0e-3f;    // q / 1e3
  const float sf = qv * fast_rcp(fmaf(Ev, Iv, 1.1920929e-7f));  // q/(E*I+eps)

  const float*    P1f = (const float*)ws;
  const uint32_t xorp = ((uint32_t)(p & 7)) << 4;

  // ---- Layer 1: lane covers point p, hidden units h = 16g + (0..15);
  //      pack 8 units per b128 write (2 writes per jet). ----
  f16x8 pl[5][2];
  #pragma unroll
  for (int hh = 0; hh < 16; ++hh) {
    const int h = 16 * g + hh;
    const float4 wv = *(const float4*)(P1f + h * 8);
    const float bb  = P1f[h * 8 + 4];
    float u0 = fmaf(wv.x, x, fmaf(wv.y, f1, fmaf(wv.z, f2, fmaf(wv.w, f3, bb))));
    float t0, t1, t2, t3, t4;
    tanh_jets(u0, wv.x, 0.f, 0.f, 0.f, t0, t1, t2, t3, t4);
    const int c = hh >> 3, j = hh & 7;
    pl[0][c][j] = (_Float16)t0;
    pl[1][c][j] = (_Float16)t1;
    pl[2][c][j] = (_Float16)t2;
    pl[3][c][j] = (_Float16)t3;
    pl[4][c][j] = (_Float16)t4;
  }
  {
    const uint32_t va0 = (uint32_t)(p * 128) + (((uint32_t)(32 * g)) ^ xorp);
    const uint32_t va1 = (uint32_t)(p * 128) + (((uint32_t)(32 * g + 16)) ^ xorp);
    #pragma unroll
    for (int k = 0; k < 5; ++k) {
      B128 t0u; t0u.v = pl[k][0];
      B128 t1u; t1u.v = pl[k][1];
      *(u128a*)(sl + va0 + k * 2048) = t0u.q;
      *(u128a*)(sl + va1 + k * 2048) = t1u.q;
    }
  }
  asm volatile("" ::: "memory");

  // ---- Layers 2 and 3 (MFMA, transposed orientation) ----
  dense_layer(sl, l, ws + 512,  b2);
  dense_layer(sl, l, ws + 2560, b3);

  // ---- Layer 4 (64 -> 1): lane handles point p, h-chunk 16g..16g+15, then reduce ----
  const uint32_t* W4p = ws + 4608;
  float w4f[16];
  #pragma unroll
  for (int d = 0; d < 8; ++d) {
    HU uu; uu.u = W4p[8 * g + d];
    w4f[2 * d]     = (float)uu.h[0];
    w4f[2 * d + 1] = (float)uu.h[1];
  }
  float zz[5];
  #pragma unroll
  for (int k = 0; k < 5; ++k) {
    const uint32_t ra0 = (uint32_t)(p * 128) + (((uint32_t)(32 * g)) ^ xorp) + (uint32_t)(k * 2048);
    const uint32_t ra1 = (uint32_t)(p * 128) + (((uint32_t)(32 * g + 16)) ^ xorp) + (uint32_t)(k * 2048);
    B128 A0, A1;
    A0.q = *(const u128a*)(sl + ra0);
    A1.q = *(const u128a*)(sl + ra1);
    float z = 0.f;
    #pragma unroll
    for (int d = 0; d < 8; ++d) z = fmaf((float)A0.v[d], w4f[d], z);
    #pragma unroll
    for (int d = 0; d < 8; ++d) z = fmaf((float)A1.v[d], w4f[8 + d], z);
    zz[k] = z;
  }
  #pragma unroll
  for (int k = 0; k < 5; ++k) {
    zz[k] += __shfl_xor(zz[k], 16, 64);
    zz[k] += __shfl_xor(zz[k], 32, 64);
  }

  if (l < 16) {
    const float psi   = zz[0] + b4[0];
    const float px    = zz[1];
    const float pxx   = 2.0f  * zz[2];
    const float pxxx  = 6.0f  * zz[3];
    const float pxxxx = 24.0f * zz[4];
    const float x2 = x * x;
    out[0 * n + i] = sf * (x2 * psi);
    out[1 * n + i] = sf * fmaf(2.0f * x, psi, x2 * px);
    out[2 * n + i] = sf * (fmaf(4.0f * x, px, 2.0f * psi) + x2 * pxx);
    out[3 * n + i] = sf * (fmaf(6.0f * x, pxx, 6.0f * px) + x2 * pxxx);
    out[4 * n + i] = sf * (fmaf(8.0f * x, pxxx, 12.0f * pxx) + x2 * pxxxx);
  }
}

extern "C" void kernel_launch(void* const* d_in, const int* in_sizes, int n_in,
                              void* d_out, int out_size, void* d_ws, size_t ws_size,
                              hipStream_t stream) {
  const float* X  = (const float*)d_in[0];
  const float* E  = (const float*)d_in[1];
  const float* I  = (const float*)d_in[2];
  const float* q  = (const float*)d_in[3];
  const float* W1 = (const float*)d_in[4];
  const float* b1 = (const float*)d_in[5];
  const float* W2 = (const float*)d_in[6];
  const float* b2 = (const float*)d_in[7];
  const float* W3 = (const float*)d_in[8];
  const float* b3 = (const float*)d_in[9];
  const float* W4 = (const float*)d_in[10];
  const float* b4 = (const float*)d_in[11];
  const int n = in_sizes[0];
  uint32_t* ws = (uint32_t*)d_ws;
  float* out = (float*)d_out;

  prep_kernel<<<dim3(1), dim3(256), 0, stream>>>(W1, b1, W2, W3, W4, ws);
  // block = 256 threads = 4 waves; each wave = 16 points -> 64 points/block
  beam_kernel<<<dim3((n + 63) / 64), dim3(256), 0, stream>>>(X, E, I, q, b2, b3, b4, ws, out, n);
}

// Round 6
// 66.618 us; speedup vs baseline: 43.5695x; 1.0464x over previous
//
#include <hip/hip_runtime.h>
#include <stdint.h>

typedef _Float16 f16x8 __attribute__((ext_vector_type(8)));
typedef float    f32x4 __attribute__((ext_vector_type(4)));
typedef uint4    u128a __attribute__((may_alias));

union HU   { uint32_t u; _Float16 h[2]; };
union B128 { uint4 q; f16x8 v; };

__device__ __forceinline__ float fast_exp2(float x) {
#if __has_builtin(__builtin_amdgcn_exp2f)
  return __builtin_amdgcn_exp2f(x);
#else
  return exp2f(x);
#endif
}
__device__ __forceinline__ float fast_rcp(float x) {
#if __has_builtin(__builtin_amdgcn_rcpf)
  return __builtin_amdgcn_rcpf(x);
#else
  return 1.0f / x;
#endif
}

// Degree-4 Taylor jet of tanh: input jet u0..u4 -> output jet t0..t4.
__device__ __forceinline__ void tanh_jets(float u0, float u1, float u2, float u3, float u4,
                                          float& t0, float& t1, float& t2, float& t3, float& t4) {
  float aa = fminf(2.8853900817779268f * u0, 126.0f);   // 2*log2(e)*u0
  float e  = fast_exp2(aa);
  float r  = fast_rcp(e + 1.0f);
  t0 = fmaf(-2.0f, r, 1.0f);                 // tanh(u0)
  float v0 = 4.0f * e * (r * r);             // sech^2(u0)
  t1 = v0 * u1;
  float v1 = -2.0f * t0 * t1;
  t2 = fmaf(u2, v0, 0.5f * u1 * v1);
  float v2 = -fmaf(2.0f * t0, t2, t1 * t1);
  t3 = fmaf(u3, v0, fmaf(0.6666666667f * u2, v1, 0.3333333333f * u1 * v2));
  float v3 = -2.0f * fmaf(t0, t3, t1 * t2);
  t4 = fmaf(u4, v0, fmaf(0.75f * u3, v1, fmaf(0.5f * u2, v2, 0.25f * u1 * v3)));
}

// ws layout (dwords). MFMA slot identity: (lane-group g = l>>4, half j, k-half s).
// A-frag for tile tm, half s: lane l supplies row mm = 16*tm + (l&15),
// half j = W[k_logical(g,j,s)][mm], where the k-permutation is chosen per layer
// to match what the B side (activations) naturally holds in registers:
//   L2: k2(g,j,s) = 16g + 8s + j            (L1 computes h = 16g + hh, hh = 8s+j)
//   L3: k3(g,j,s) = 32s + 16*(j>>2) + 4g + (j&3)   (L2's C-frag: h = 16tm+4g+r)
//   [0    .. 511 ]  P1: [h][8] floats = {W1[0][h],W1[1][h],W1[2][h],W1[3][h],b1[h],0,0,0}
//   [512  .. 2559]  W2 A-frags (frag fi = tm*2+s, lane l, dword pj)
//   [2560 .. 4607]  W3 A-frags (same shape, k3 permutation)
//   [4608 .. 4671]  W4 as plain f32[64]
__global__ void prep_kernel(const float* __restrict__ W1, const float* __restrict__ b1,
                            const float* __restrict__ W2, const float* __restrict__ W3,
                            const float* __restrict__ W4, uint32_t* __restrict__ ws) {
  const int t = threadIdx.x;  // 256 threads, 1 block
  float* P1 = (float*)ws;
  if (t < 64) {
    P1[t * 8 + 0] = W1[0 * 64 + t];
    P1[t * 8 + 1] = W1[1 * 64 + t];
    P1[t * 8 + 2] = W1[2 * 64 + t];
    P1[t * 8 + 3] = W1[3 * 64 + t];
    P1[t * 8 + 4] = b1[t];
    P1[t * 8 + 5] = 0.f; P1[t * 8 + 6] = 0.f; P1[t * 8 + 7] = 0.f;
  }
  for (int idx = t; idx < 2048; idx += 256) {
    const int fi = idx >> 8;            // frag index 0..7 = tm*2 + s
    const int tm = fi >> 1, s = fi & 1;
    const int l  = (idx >> 2) & 63;     // lane
    const int pj = idx & 3;             // dword: halves j0=2pj, j0+1
    const int g  = l >> 4;
    const int mm = 16 * tm + (l & 15);  // h_out row
    const int j0 = 2 * pj, j1 = 2 * pj + 1;
    // L2 k-permutation
    const int k2a = 16 * g + 8 * s + j0;
    const int k2b = 16 * g + 8 * s + j1;
    HU a; a.h[0] = (_Float16)W2[k2a * 64 + mm]; a.h[1] = (_Float16)W2[k2b * 64 + mm];
    ws[512 + idx] = a.u;
    // L3 k-permutation
    const int k3a = 32 * s + 16 * (j0 >> 2) + 4 * g + (j0 & 3);
    const int k3b = 32 * s + 16 * (j1 >> 2) + 4 * g + (j1 & 3);
    HU b; b.h[0] = (_Float16)W3[k3a * 64 + mm]; b.h[1] = (_Float16)W3[k3b * 64 + mm];
    ws[2560 + idx] = b.u;
  }
  if (t < 64) {
    ws[4608 + t] = __float_as_uint(W4[t]);
  }
}

#define MFMA16(A, B, C) __builtin_amdgcn_mfma_f32_16x16x32_f16((A), (B), (C), 0, 0, 0)

__global__ __launch_bounds__(256, 3)
void beam_kernel(const float* __restrict__ X, const float* __restrict__ Ein,
                 const float* __restrict__ Iin, const float* __restrict__ Qin,
                 const float* __restrict__ b2, const float* __restrict__ b3,
                 const float* __restrict__ b4, const uint32_t* __restrict__ ws,
                 float* __restrict__ out, int n) {
  const int tid = threadIdx.x;
  const int w   = tid >> 6;
  const int l   = tid & 63;
  const int g   = l >> 4;
  const int p   = l & 15;
  int i = (blockIdx.x * 4 + w) * 16 + p;
  if (i >= n) i = n - 1;

  const float x  = X[i];
  const float Ev = Ein[i], Iv = Iin[i], qv = Qin[i];
  const float f1 = Ev * 5.0e-12f;   // E / 2e11
  const float f2 = Iv * 1.0e6f;     // I / 1e-6
  const float f3 = qv * 1.0e-3f;    // q / 1e3
  const float sf = qv * fast_rcp(fmaf(Ev, Iv, 1.1920929e-7f));  // q/(E*I+eps)

  const float* P1f = (const float*)ws;
  const float* W4f = (const float*)(ws + 4608);

  // ---- Layer 1: lane (g,p) computes h = 16g + hh for point p; results go
  //      DIRECTLY into L2's B-fragments: bf2[jet][s] half j, h = 16g+8s+j ----
  f16x8 bf2[5][2];
  #pragma unroll
  for (int hh = 0; hh < 16; ++hh) {
    const int h = 16 * g + hh;
    const int s = hh >> 3, j = hh & 7;
    const float4 wv = *(const float4*)(P1f + h * 8);
    const float bb  = P1f[h * 8 + 4];
    float u0 = fmaf(wv.x, x, fmaf(wv.y, f1, fmaf(wv.z, f2, fmaf(wv.w, f3, bb))));
    float t0, t1, t2, t3, t4;
    tanh_jets(u0, wv.x, 0.f, 0.f, 0.f, t0, t1, t2, t3, t4);
    bf2[0][s][j] = (_Float16)t0;
    bf2[1][s][j] = (_Float16)t1;
    bf2[2][s][j] = (_Float16)t2;
    bf2[3][s][j] = (_Float16)t3;
    bf2[4][s][j] = (_Float16)t4;
  }

  // ---- Layer 2 (MFMA): C = W2(A) x T(B). C: col = p, row h_out = 16tm+4g+r ----
  f32x4 acc[5][4];
  #pragma unroll
  for (int tm = 0; tm < 4; ++tm) {
    const float4 bv = *(const float4*)(b2 + 16 * tm + 4 * g);
    acc[0][tm] = (f32x4){bv.x, bv.y, bv.z, bv.w};
    #pragma unroll
    for (int k = 1; k < 5; ++k) acc[k][tm] = (f32x4){0.f, 0.f, 0.f, 0.f};
  }
  #pragma unroll
  for (int s = 0; s < 2; ++s) {
    #pragma unroll
    for (int tm = 0; tm < 4; ++tm) {
      B128 af; af.q = *(const u128a*)(ws + 512 + ((tm * 2 + s) * 64 + l) * 4);
      #pragma unroll
      for (int k = 0; k < 5; ++k)
        acc[k][tm] = MFMA16(af.v, bf2[k][s], acc[k][tm]);
    }
  }

  // ---- tanh jets; pack straight into L3's B-frags:
  //      slot (s = tm>>1, j = 4*(tm&1)+r) carries h = 16tm+4g+r = k3(g,j,s) ----
  f16x8 bf3[5][2];
  #pragma unroll
  for (int tm = 0; tm < 4; ++tm) {
    const int s = tm >> 1, jb = 4 * (tm & 1);
    #pragma unroll
    for (int r = 0; r < 4; ++r) {
      float t0, t1, t2, t3, t4;
      tanh_jets(acc[0][tm][r], acc[1][tm][r], acc[2][tm][r], acc[3][tm][r], acc[4][tm][r],
                t0, t1, t2, t3, t4);
      bf3[0][s][jb + r] = (_Float16)t0;
      bf3[1][s][jb + r] = (_Float16)t1;
      bf3[2][s][jb + r] = (_Float16)t2;
      bf3[3][s][jb + r] = (_Float16)t3;
      bf3[4][s][jb + r] = (_Float16)t4;
    }
  }

  // ---- Layer 3 (MFMA) ----
  #pragma unroll
  for (int tm = 0; tm < 4; ++tm) {
    const float4 bv = *(const float4*)(b3 + 16 * tm + 4 * g);
    acc[0][tm] = (f32x4){bv.x, bv.y, bv.z, bv.w};
    #pragma unroll
    for (int k = 1; k < 5; ++k) acc[k][tm] = (f32x4){0.f, 0.f, 0.f, 0.f};
  }
  #pragma unroll
  for (int s = 0; s < 2; ++s) {
    #pragma unroll
    for (int tm = 0; tm < 4; ++tm) {
      B128 af; af.q = *(const u128a*)(ws + 2560 + ((tm * 2 + s) * 64 + l) * 4);
      #pragma unroll
      for (int k = 0; k < 5; ++k)
        acc[k][tm] = MFMA16(af.v, bf3[k][s], acc[k][tm]);
    }
  }

  // ---- tanh jets in place (f32, no f16 rounding before L4) ----
  #pragma unroll
  for (int tm = 0; tm < 4; ++tm) {
    #pragma unroll
    for (int r = 0; r < 4; ++r) {
      float t0, t1, t2, t3, t4;
      tanh_jets(acc[0][tm][r], acc[1][tm][r], acc[2][tm][r], acc[3][tm][r], acc[4][tm][r],
                t0, t1, t2, t3, t4);
      acc[0][tm][r] = t0; acc[1][tm][r] = t1; acc[2][tm][r] = t2;
      acc[3][tm][r] = t3; acc[4][tm][r] = t4;
    }
  }

  // ---- Layer 4 (64 -> 1): per-lane partial over held h = 16tm+4g+r, then
  //      butterfly-reduce across the 4 lanes sharing point p ----
  float zz[5] = {0.f, 0.f, 0.f, 0.f, 0.f};
  #pragma unroll
  for (int tm = 0; tm < 4; ++tm) {
    const float4 wv = *(const float4*)(W4f + 16 * tm + 4 * g);
    #pragma unroll
    for (int k = 0; k < 5; ++k) {
      zz[k] = fmaf(wv.x, acc[k][tm][0], zz[k]);
      zz[k] = fmaf(wv.y, acc[k][tm][1], zz[k]);
      zz[k] = fmaf(wv.z, acc[k][tm][2], zz[k]);
      zz[k] = fmaf(wv.w, acc[k][tm][3], zz[k]);
    }
  }
  #pragma unroll
  for (int k = 0; k < 5; ++k) {
    zz[k] += __shfl_xor(zz[k], 16, 64);
    zz[k] += __shfl_xor(zz[k], 32, 64);
  }

  if (l < 16) {
    const float psi   = zz[0] + b4[0];
    const float px    = zz[1];
    const float pxx   = 2.0f  * zz[2];
    const float pxxx  = 6.0f  * zz[3];
    const float pxxxx = 24.0f * zz[4];
    const float x2 = x * x;
    out[0 * n + i] = sf * (x2 * psi);
    out[1 * n + i] = sf * fmaf(2.0f * x, psi, x2 * px);
    out[2 * n + i] = sf * (fmaf(4.0f * x, px, 2.0f * psi) + x2 * pxx);
    out[3 * n + i] = sf * (fmaf(6.0f * x, pxx, 6.0f * px) + x2 * pxxx);
    out[4 * n + i] = sf * (fmaf(8.0f * x, pxxx, 12.0f * pxx) + x2 * pxxxx);
  }
}

extern "C" void kernel_launch(void* const* d_in, const int* in_sizes, int n_in,
                              void* d_out, int out_size, void* d_ws, size_t ws_size,
                              hipStream_t stream) {
  const float* X  = (const float*)d_in[0];
  const float* E  = (const float*)d_in[1];
  const float* I  = (const float*)d_in[2];
  const float* q  = (const float*)d_in[3];
  const float* W1 = (const float*)d_in[4];
  const float* b1 = (const float*)d_in[5];
  const float* W2 = (const float*)d_in[6];
  const float* b2 = (const float*)d_in[7];
  const float* W3 = (const float*)d_in[8];
  const float* b3 = (const float*)d_in[9];
  const float* W4 = (const float*)d_in[10];
  const float* b4 = (const float*)d_in[11];
  const int n = in_sizes[0];
  uint32_t* ws = (uint32_t*)d_ws;
  float* out = (float*)d_out;

  prep_kernel<<<dim3(1), dim3(256), 0, stream>>>(W1, b1, W2, W3, W4, ws);
  // block = 256 threads = 4 waves; each wave = 16 points -> 64 points/block
  beam_kernel<<<dim3((n + 63) / 64), dim3(256), 0, stream>>>(X, E, I, q, b2, b3, b4, ws, out, n);
}